// Round 2
// baseline (184476.270 us; speedup 1.0000x reference)
//
#include <hip/hip_runtime.h>
#include <math.h>

// CRvNN forward, full f32. N=64, S=130 (augmented), D=1024, 25 steps.
// Workspace (floats), U = 8320*1024 = 8,519,680:
//  sq[0,U) | l1[U,2U) | r1[2U,3U) | l2[3U,4U) | r2[4U,5U)
//  l2/r2 double as hid-chunk/cont-chunk during the cell pipeline (disjoint lifetime).
//  Tail: Lm, Rm (64*130*132 each), maskv/sel/lastm/endm/ep/sc/tp (MM each),
//  spart (MM*8), um(64), part(64), gmx(4), flag(int).  Total ~172 MB.

#define NB 64
#define SS 130
#define DD 1024
#define MM (NB*SS)
#define LSTR 132
#define CROWS 1664   // 13 row-tiles per cell chunk; 5 chunks cover 8320

struct GemmSrc { const float* a[5]; };

__device__ __forceinline__ float bsum(float v){
  __shared__ float sh[4];
  __syncthreads();
  #pragma unroll
  for (int o=32;o;o>>=1) v += __shfl_down(v,o);
  if ((threadIdx.x & 63)==0) sh[threadIdx.x>>6] = v;
  __syncthreads();
  return sh[0]+sh[1]+sh[2]+sh[3];
}
__device__ __forceinline__ float bmaxr(float v){
  __shared__ float sh[4];
  __syncthreads();
  #pragma unroll
  for (int o=32;o;o>>=1) v = fmaxf(v,__shfl_down(v,o));
  if ((threadIdx.x & 63)==0) sh[threadIdx.x>>6] = v;
  __syncthreads();
  return fmaxf(fmaxf(sh[0],sh[1]),fmaxf(sh[2],sh[3]));
}
__device__ __forceinline__ float gelu_(float x){
  return 0.5f*x*(1.f+erff(x*0.70710678118654752f));
}

// ---------------- masks / augment ----------------
__global__ __launch_bounds__(256) void build_masks(
    const float* __restrict__ im, float* __restrict__ mk, float* __restrict__ sel,
    float* __restrict__ lastm, float* __restrict__ endm, float* __restrict__ ep,
    float* __restrict__ um, int* __restrict__ flag){
  int b = blockIdx.x, i = threadIdx.x;
  if (i < SS){
    float mye = (i<=1) ? 1.f : im[b*128 + (i-2)];
    float mne = (i==SS-1) ? 0.f : ((i==0) ? 1.f : im[b*128 + (i-1)]);
    float em  = mye - mne;
    float mns = (i==0) ? 0.f : mye;
    float lm;
    if (i < SS-1){
      int i1 = i+1;
      float mye1 = (i1<=1) ? 1.f : im[b*128 + (i1-2)];
      float mne1 = (i1==SS-1) ? 0.f : im[b*128 + (i1-1)];
      lm = mye1 - mne1;
    } else lm = 0.f;
    float sl = mns * mne * (1.f - lm);
    int idx = b*SS + i;
    mk[idx]=mye; sel[idx]=sl; lastm[idx]=lm; endm[idx]=em; ep[idx]=mye;
  } else if (i == SS) { um[b] = 1.f; }
  else if (i == SS+1 && b==0) { flag[0] = 0; }
}

__global__ __launch_bounds__(256) void build_seq(
    const float* __restrict__ seqin, const float* __restrict__ START,
    const float* __restrict__ END, const float* __restrict__ mk,
    const float* __restrict__ endm, float* __restrict__ out){
  int r = blockIdx.x; int b = r/SS, i = r%SS; int t = threadIdx.x;
  float em = endm[r], m = mk[r];
  #pragma unroll
  for (int q=0;q<4;q++){
    int j = t + q*256;
    float v;
    if (i==0) v = START[j];
    else if (i<=128) v = seqin[((size_t)b*128 + (i-1))*DD + j];
    else v = 0.f;
    v = em*END[j] + (1.f-em)*v;
    out[(size_t)r*DD + j] = v*m;
  }
}

// ---- main GEMM (f32, 128x128 tile, BK=16, 8x8 micro) ----
// act: 0 = store, 1 = gelu+store, 2 = gelu then fused scorer partial (no C store)
__global__ __launch_bounds__(256,2) void gemm_f32(
    GemmSrc S, long lda, const float* __restrict__ B, const float* __restrict__ bias,
    float* __restrict__ C, long ldc, int N, int K, int act,
    const int* __restrict__ flag, float* __restrict__ spart, const float* __restrict__ Ws){
  if (flag[0]) return;
  __shared__ float Asm[16][132];
  __shared__ float Bsm[16][132];
  float acc[8][8];
  #pragma unroll
  for (int i=0;i<8;i++)
    #pragma unroll
    for (int j=0;j<8;j++) acc[i][j]=0.f;
  const int t = threadIdx.x;
  const int tx = t & 15, ty = t >> 4;
  const long mb = (long)blockIdx.y * 128;
  const int  nb = blockIdx.x * 128;
  for (int kt=0; kt<K; kt+=16){
    #pragma unroll
    for (int ii=0; ii<2; ii++){
      int f  = t + 256*ii;
      int m  = f >> 2;
      int k4 = (f & 3) * 4;
      int kg = kt + k4;
      const float* src = S.a[kg >> 10];
      float4 v = *(const float4*)(src + (mb + m)*lda + (kg & 1023));
      Asm[k4+0][m]=v.x; Asm[k4+1][m]=v.y; Asm[k4+2][m]=v.z; Asm[k4+3][m]=v.w;
    }
    #pragma unroll
    for (int ii=0; ii<2; ii++){
      int f  = t + 256*ii;
      int kk = f >> 5;
      int c4 = (f & 31)*4;
      *(float4*)&Bsm[kk][c4] = *(const float4*)(B + (long)(kt+kk)*N + nb + c4);
    }
    __syncthreads();
    #pragma unroll
    for (int kk=0;kk<16;kk++){
      float av[8], bv[8];
      *(float4*)&av[0] = *(const float4*)&Asm[kk][ty*4];
      *(float4*)&av[4] = *(const float4*)&Asm[kk][64+ty*4];
      *(float4*)&bv[0] = *(const float4*)&Bsm[kk][tx*4];
      *(float4*)&bv[4] = *(const float4*)&Bsm[kk][64+tx*4];
      #pragma unroll
      for (int r=0;r<8;r++)
        #pragma unroll
        for (int c=0;c<8;c++) acc[r][c] = fmaf(av[r],bv[c],acc[r][c]);
    }
    __syncthreads();
  }
  if (act==2){
    // fused gelu + scorer dot: deterministic fixed-order butterfly over the
    // 16 lanes (tx) that share each output row.
    #pragma unroll
    for (int rh=0;rh<2;rh++)
    #pragma unroll
    for (int rr=0;rr<4;rr++){
      float s = 0.f;
      #pragma unroll
      for (int ch=0;ch<2;ch++){
        #pragma unroll
        for (int q=0;q<4;q++){
          int col = nb + ch*64 + tx*4 + q;
          float v = gelu_(acc[rh*4+rr][ch*4+q] + bias[col]);
          s = fmaf(v, Ws[col], s);
        }
      }
      s += __shfl_xor(s,1); s += __shfl_xor(s,2);
      s += __shfl_xor(s,4); s += __shfl_xor(s,8);
      if (tx==0) spart[(size_t)(mb + rh*64 + ty*4 + rr)*8 + blockIdx.x] = s;
    }
    return;
  }
  #pragma unroll
  for (int rh=0;rh<2;rh++)
  #pragma unroll
  for (int rr=0;rr<4;rr++){
    long row = mb + rh*64 + ty*4 + rr;
    #pragma unroll
    for (int ch=0;ch<2;ch++){
      int col = nb + ch*64 + tx*4;
      float t0 = acc[rh*4+rr][ch*4+0] + bias[col+0];
      float t1 = acc[rh*4+rr][ch*4+1] + bias[col+1];
      float t2 = acc[rh*4+rr][ch*4+2] + bias[col+2];
      float t3 = acc[rh*4+rr][ch*4+3] + bias[col+3];
      if (act==1){ t0=gelu_(t0); t1=gelu_(t1); t2=gelu_(t2); t3=gelu_(t3); }
      float4 v; v.x=t0; v.y=t1; v.z=t2; v.w=t3;
      *(float4*)(C + row*ldc + col) = v;
    }
  }
}

// ---- batched neighbor GEMM: Y[b] = P[b](130x130,pad132) @ X[b](130x1024) ----
__global__ __launch_bounds__(256,2) void bgemm(
    const float* __restrict__ P, const float* __restrict__ X, float* __restrict__ Y,
    const int* __restrict__ flag){
  if (flag[0]) return;
  __shared__ float Ps[64][17];
  __shared__ float Xs[16][132];
  const int t = threadIdx.x;
  const int nt = blockIdx.x, mt = blockIdx.y, b = blockIdx.z;
  const int i0 = mt*64;
  const float* Pb = P + (size_t)b*SS*LSTR;
  const float* Xb = X + (size_t)b*SS*DD + nt*128;
  float* Yb = Y + (size_t)b*SS*DD + nt*128;
  const int tx = t & 7, ty = t >> 3;
  float acc[2][16];
  #pragma unroll
  for (int r=0;r<2;r++)
    #pragma unroll
    for (int c=0;c<16;c++) acc[r][c]=0.f;
  for (int j0=0;j0<SS;j0+=16){
    { int r = t>>2, c0 = (t&3)*4;
      float4 v = make_float4(0.f,0.f,0.f,0.f);
      if (i0 + r < SS && j0 + c0 < LSTR) v = *(const float4*)(Pb + (size_t)(i0+r)*LSTR + j0 + c0);
      Ps[r][c0]=v.x; Ps[r][c0+1]=v.y; Ps[r][c0+2]=v.z; Ps[r][c0+3]=v.w;
    }
    #pragma unroll
    for (int ii=0;ii<2;ii++){
      int f = t + 256*ii;
      int jj = f>>5, c4 = (f&31)*4;
      float4 v = make_float4(0.f,0.f,0.f,0.f);
      if (j0 + jj < SS) v = *(const float4*)(Xb + (size_t)(j0+jj)*DD + c4);
      *(float4*)&Xs[jj][c4] = v;
    }
    __syncthreads();
    #pragma unroll
    for (int jj=0;jj<16;jj++){
      float p0 = Ps[2*ty][jj], p1 = Ps[2*ty+1][jj];
      #pragma unroll
      for (int q=0;q<4;q++){
        float4 xv = *(const float4*)&Xs[jj][tx*4 + 32*q];
        acc[0][q*4+0] = fmaf(p0,xv.x,acc[0][q*4+0]);
        acc[0][q*4+1] = fmaf(p0,xv.y,acc[0][q*4+1]);
        acc[0][q*4+2] = fmaf(p0,xv.z,acc[0][q*4+2]);
        acc[0][q*4+3] = fmaf(p0,xv.w,acc[0][q*4+3]);
        acc[1][q*4+0] = fmaf(p1,xv.x,acc[1][q*4+0]);
        acc[1][q*4+1] = fmaf(p1,xv.y,acc[1][q*4+1]);
        acc[1][q*4+2] = fmaf(p1,xv.z,acc[1][q*4+2]);
        acc[1][q*4+3] = fmaf(p1,xv.w,acc[1][q*4+3]);
      }
    }
    __syncthreads();
  }
  #pragma unroll
  for (int rr=0;rr<2;rr++){
    int row = i0 + 2*ty + rr;
    if (row < SS){
      #pragma unroll
      for (int q=0;q<4;q++){
        float4 v = make_float4(acc[rr][q*4],acc[rr][q*4+1],acc[rr][q*4+2],acc[rr][q*4+3]);
        *(float4*)(Yb + (size_t)row*DD + tx*4 + 32*q) = v;
      }
    }
  }
}

// ---------------- neighbor probabilities ----------------
__global__ void neighbor_kernel(const float* __restrict__ ep, const float* __restrict__ mk,
                                float* __restrict__ L, float* __restrict__ R,
                                const int* __restrict__ flag){
  if (flag[0]) return;
  int idx = blockIdx.x*blockDim.x + threadIdx.x;
  if (idx >= MM) return;
  int b = idx / SS, i = idx % SS;
  const float* p = ep + b*SS;
  const float* m = mk + b*SS;
  float* Lr = L + (size_t)idx*LSTR;
  float* Rr = R + (size_t)idx*LSTR;
  for (int j=0;j<LSTR;j++){ Lr[j]=0.f; Rr[j]=0.f; }
  float cs=0.f;
  for (int j=i+1;j<SS;j++){
    float mat = p[j]*m[j];
    cs += mat;
    float v = (cs>1.f) ? fmaxf(1.f-(cs-mat),0.f) : mat;
    Rr[j] = v*m[j];
  }
  cs=0.f;
  for (int j=i-1;j>=0;j--){
    float mat = p[j]*m[j];
    cs += mat;
    float v = (cs>1.f) ? fmaxf(1.f-(cs-mat),0.f) : mat;
    Lr[j] = v*m[j];
  }
}

// ---------------- LN after init ----------------
__global__ __launch_bounds__(256) void ln1_kernel(
    const float* __restrict__ xin, const float* __restrict__ g, const float* __restrict__ bb,
    const float* __restrict__ mk, float* __restrict__ out){
  int r = blockIdx.x, t = threadIdx.x;
  const float* xr = xin + (size_t)r*DD;
  float x[4]; float s=0.f;
  #pragma unroll
  for (int q=0;q<4;q++){ x[q]=xr[t+256*q]; s+=x[q]; }
  float mean = bsum(s)*(1.f/DD);
  float vs=0.f;
  #pragma unroll
  for (int q=0;q<4;q++){ float d=x[q]-mean; vs+=d*d; }
  float var = bsum(vs)*(1.f/DD);
  float inv = 1.f/sqrtf(var+1e-5f);
  float m = mk[r];
  #pragma unroll
  for (int q=0;q<4;q++){ int j=t+256*q; out[(size_t)r*DD+j] = ((x[q]-mean)*inv*g[j]+bb[j])*m; }
}

// ---------------- scorer finalize / max / tp ----------------
__global__ void scorer_final(const float* __restrict__ spart, const float* __restrict__ bs,
                             float* __restrict__ sc, const int* __restrict__ flag){
  if (flag[0]) return;
  int r = blockIdx.x*blockDim.x + threadIdx.x;
  if (r >= MM) return;
  float s = bs[0];
  #pragma unroll
  for (int k=0;k<8;k++) s += spart[(size_t)r*8+k];
  sc[r] = s;
}
__global__ __launch_bounds__(256) void max1(const float* __restrict__ sc, float* __restrict__ part,
                                            const int* __restrict__ flag){
  if (flag[0]) return;
  int idx = blockIdx.x*256 + threadIdx.x;
  float v = -1e30f;
  for (int i = idx; i < MM; i += 64*256) v = fmaxf(v, sc[i]);
  v = bmaxr(v);
  if (threadIdx.x==0) part[blockIdx.x] = v;
}
__global__ __launch_bounds__(64) void max2(const float* __restrict__ part, float* __restrict__ gm,
                                           const int* __restrict__ flag){
  if (flag[0]) return;
  float v = part[threadIdx.x];
  #pragma unroll
  for (int o=32;o;o>>=1) v = fmaxf(v, __shfl_down(v,o));
  if (threadIdx.x==0) gm[0] = fmaxf(v, 0.f);
}
__global__ void tp_kernel(const float* __restrict__ sc, const float* __restrict__ sel,
                          const float* __restrict__ um, const float* __restrict__ gm,
                          float* __restrict__ tp, const int* __restrict__ flag){
  if (flag[0]) return;
  int idx = blockIdx.x*blockDim.x + threadIdx.x;
  if (idx>=MM) return;
  int b = idx / SS;
  float g = gm[0];
  float et = expf(sc[idx]-g)*sel[idx];
  float en = expf(-g);
  tp[idx] = et/(et+en+2e-8f)*um[b];
}

// ---------------- gates + LN + blend (in-place sq), row-chunked ----------------
__global__ __launch_bounds__(256) void update_kernel(
    const float* __restrict__ cont, const float* __restrict__ l1, float* __restrict__ sq,
    const float* __restrict__ tp, const float* __restrict__ g, const float* __restrict__ bb,
    const int* __restrict__ flag, long row0){
  if (flag[0]) return;
  long r = row0 + blockIdx.x; int t = threadIdx.x;
  const float* cr = cont + (size_t)blockIdx.x*4096;
  const float* lr = l1 + (size_t)r*DD;
  float* sr = sq + (size_t)r*DD;
  float x[4], sv[4];
  float s=0.f;
  #pragma unroll
  for (int q=0;q<4;q++){
    int j = t+q*256;
    float c0=cr[j], c1=cr[DD+j], c2=cr[2*DD+j], c3=cr[3*DD+j];
    float g0=1.f/(1.f+expf(-c0));
    float g1=1.f/(1.f+expf(-c1));
    float g2=1.f/(1.f+expf(-c2));
    float lv=lr[j]; float sqv=sr[j]; sv[q]=sqv;
    x[q] = g0*lv + g1*sqv + g2*c3;
    s += x[q];
  }
  float mean = bsum(s)*(1.f/DD);
  float vs=0.f;
  #pragma unroll
  for (int q=0;q<4;q++){ float d=x[q]-mean; vs+=d*d; }
  float var = bsum(vs)*(1.f/DD);
  float inv = 1.f/sqrtf(var+1e-5f);
  float tpv = tp[r];
  #pragma unroll
  for (int q=0;q<4;q++){
    int j=t+q*256;
    float comp = (x[q]-mean)*inv*g[j]+bb[j];
    sr[j] = tpv*comp + (1.f-tpv)*sv[q];
  }
}

// ---------------- ep / active / done ----------------
__global__ void ep_update(float* __restrict__ ep, const float* __restrict__ R,
                          const float* __restrict__ tp, const int* __restrict__ flag){
  if (flag[0]) return;
  int idx = blockIdx.x*blockDim.x + threadIdx.x;
  if (idx>=MM) return;
  int b = idx / SS;
  const float* Rr = R + (size_t)idx*LSTR;
  const float* tb = tp + b*SS;
  float d=0.f;
  for (int j=0;j<SS;j++) d = fmaf(Rr[j],tb[j],d);
  ep[idx] *= (1.f - d);
}
__global__ __launch_bounds__(256) void active_um(const float* __restrict__ ep,
                                                 const float* __restrict__ sel,
                                                 float* __restrict__ um,
                                                 const int* __restrict__ flag){
  if (flag[0]) return;
  int b = blockIdx.x, t = threadIdx.x;
  float s = (t<SS) ? ep[b*SS+t]*sel[b*SS+t] : 0.f;
  s = bsum(s);
  if (t==0) um[b] *= (s >= 0.1f) ? 1.f : 0.f;
}
__global__ __launch_bounds__(64) void done_kernel(const float* __restrict__ um, int* __restrict__ flag){
  float v = um[threadIdx.x];
  unsigned long long b = __ballot(v > 0.f);
  if (threadIdx.x==0) flag[0] = (b==0ULL) ? 1 : 0;
}

// ---------------- outputs ----------------
__global__ __launch_bounds__(256) void output_kernel(const float* __restrict__ sq,
                                                     const float* __restrict__ mk,
                                                     float* __restrict__ out){
  int r = blockIdx.x; int b = r/SS, i = r%SS;
  if (i<1 || i>128) return;
  float m = mk[r]; int t=threadIdx.x;
  #pragma unroll
  for (int q=0;q<4;q++){
    int j = t+q*256;
    out[((size_t)b*128 + (i-1))*DD + j] = sq[(size_t)r*DD + j]*m;
  }
}
__global__ __launch_bounds__(256) void gstate_kernel(const float* __restrict__ sq,
                                                     const float* __restrict__ mk,
                                                     const float* __restrict__ lastm,
                                                     float* __restrict__ outg){
  int b = blockIdx.x; int t=threadIdx.x;
  #pragma unroll
  for (int q=0;q<4;q++){
    int j = t+q*256;
    float acc=0.f;
    for (int i=0;i<SS;i++){
      float w = lastm[b*SS+i]*mk[b*SS+i];
      acc = fmaf(w, sq[((size_t)(b*SS+i))*DD + j], acc);
    }
    outg[(size_t)b*DD + j] = acc;
  }
}

extern "C" void kernel_launch(void* const* d_in, const int* in_sizes, int n_in,
                              void* d_out, int out_size, void* d_ws, size_t ws_size,
                              hipStream_t stream) {
  const float* sequence   = (const float*)d_in[0];
  const float* input_mask = (const float*)d_in[1];
  const float* START      = (const float*)d_in[2];
  const float* END        = (const float*)d_in[3];
  const float* W_conv     = (const float*)d_in[4];
  const float* b_conv     = (const float*)d_in[5];
  const float* W_scorer   = (const float*)d_in[6];
  const float* b_scorer   = (const float*)d_in[7];
  const float* W_init     = (const float*)d_in[8];
  const float* b_init     = (const float*)d_in[9];
  const float* W_cell1    = (const float*)d_in[10];
  const float* b_cell1    = (const float*)d_in[11];
  const float* W_cell2    = (const float*)d_in[12];
  const float* b_cell2    = (const float*)d_in[13];
  const float* ln1g       = (const float*)d_in[14];
  const float* ln1b       = (const float*)d_in[15];
  const float* ln2g       = (const float*)d_in[16];
  const float* ln2b       = (const float*)d_in[17];

  float* ws = (float*)d_ws;
  const size_t U = (size_t)MM*DD;
  float* sq   = ws;
  float* l1   = ws + U;
  float* r1   = ws + 2*U;
  float* l2   = ws + 3*U;   // also hid-chunk (1664*4096 <= U)
  float* r2   = ws + 4*U;   // also cont-chunk
  float* Lm   = ws + 5*U;
  float* Rm   = Lm + (size_t)NB*SS*LSTR;
  float* maskv= Rm + (size_t)NB*SS*LSTR;
  float* sel  = maskv + MM;
  float* lastm= sel + MM;
  float* endm = lastm + MM;
  float* ep   = endm + MM;
  float* scb  = ep + MM;
  float* tpb  = scb + MM;
  float* spart= tpb + MM;          // MM*8
  float* umb  = spart + (size_t)MM*8;
  float* part = umb + NB;
  float* gmx  = part + 64;
  int*   flag = (int*)(gmx + 4);

  build_masks<<<NB,256,0,stream>>>(input_mask, maskv, sel, lastm, endm, ep, umb, flag);
  build_seq<<<MM,256,0,stream>>>(sequence, START, END, maskv, endm, r1);
  GemmSrc si; si.a[0]=r1; si.a[1]=r1; si.a[2]=r1; si.a[3]=r1; si.a[4]=r1;
  gemm_f32<<<dim3(8,65),256,0,stream>>>(si, DD, W_init, b_init, l2, DD, DD, DD, 0, flag, nullptr, nullptr);
  ln1_kernel<<<MM,256,0,stream>>>(l2, ln1g, ln1b, maskv, sq);

  for (int it=0; it<25; ++it){
    neighbor_kernel<<<(MM+255)/256,256,0,stream>>>(ep, maskv, Lm, Rm, flag);
    bgemm<<<dim3(8,3,NB),256,0,stream>>>(Lm, sq, l1, flag);
    bgemm<<<dim3(8,3,NB),256,0,stream>>>(Rm, sq, r1, flag);
    bgemm<<<dim3(8,3,NB),256,0,stream>>>(Lm, l1, l2, flag);
    bgemm<<<dim3(8,3,NB),256,0,stream>>>(Rm, r1, r2, flag);
    GemmSrc s5; s5.a[0]=l2; s5.a[1]=l1; s5.a[2]=sq; s5.a[3]=r1; s5.a[4]=r2;
    gemm_f32<<<dim3(8,65),256,0,stream>>>(s5, DD, W_conv, b_conv, nullptr, DD, DD, 5*DD, 2, flag, spart, W_scorer);
    scorer_final<<<(MM+255)/256,256,0,stream>>>(spart, b_scorer, scb, flag);
    max1<<<64,256,0,stream>>>(scb, part, flag);
    max2<<<1,64,0,stream>>>(part, gmx, flag);
    tp_kernel<<<(MM+255)/256,256,0,stream>>>(scb, sel, umb, gmx, tpb, flag);
    // cell1 -> cell2 -> update, chunked over rows (l2/r2 reused as hid/cont)
    for (int c=0;c<5;c++){
      long row0 = (long)c*CROWS;
      GemmSrc s2; s2.a[0]=l1+row0*DD; s2.a[1]=sq+row0*DD; s2.a[2]=s2.a[1]; s2.a[3]=s2.a[1]; s2.a[4]=s2.a[1];
      gemm_f32<<<dim3(32,13),256,0,stream>>>(s2, DD, W_cell1, b_cell1, l2, 4096, 4096, 2048, 1, flag, nullptr, nullptr);
      GemmSrc s3; s3.a[0]=l2; s3.a[1]=l2+DD; s3.a[2]=l2+2*DD; s3.a[3]=l2+3*DD; s3.a[4]=l2;
      gemm_f32<<<dim3(32,13),256,0,stream>>>(s3, 4096, W_cell2, b_cell2, r2, 4096, 4096, 4096, 0, flag, nullptr, nullptr);
      update_kernel<<<CROWS,256,0,stream>>>(r2, l1, sq, tpb, ln2g, ln2b, flag, row0);
    }
    ep_update<<<(MM+255)/256,256,0,stream>>>(ep, Rm, tpb, flag);
    active_um<<<NB,256,0,stream>>>(ep, sel, umb, flag);
    done_kernel<<<1,64,0,stream>>>(umb, flag);
  }

  float* out = (float*)d_out;
  output_kernel<<<MM,256,0,stream>>>(sq, maskv, out);
  gstate_kernel<<<NB,256,0,stream>>>(sq, maskv, lastm, out + (size_t)NB*128*DD);
}

// Round 4
// 181382.812 us; speedup vs baseline: 1.0171x; 1.0171x over previous
//
#include <hip/hip_runtime.h>
#include <math.h>

// CRvNN forward. N=64, S=130 (augmented), D=1024, 25 steps.
// f32 everywhere except the 3 big GEMMs, which use f16 hi/lo split MFMA with
// renormalized planes (W x64, lo x2048) to keep all f16 values normal:
//   D = (Wh*Ah)/64 + (Wh*Al + Wl*Ah)/131072,  error ~ 2^-22 (dropped lo*lo).
// Workspace (floats), U = 8320*1024:
//  sq[0,U) | l1[U,2U) | r1[2U,3U) | l2[3U,4U) | r2[4U,5U)
//  l2/r2 double as hid-chunk/cont-chunk during the cell pipeline.
//  Tail: Lm/Rm, masks, sc/tp, spart(MM*16), um/part/gmx/flag,
//  then (MFMA mode only) W^T f16 hi/lo planes for W_conv/W_cell1/W_cell2.

#define NB 64
#define SS 130
#define DD 1024
#define MM (NB*SS)
#define LSTR 132
#define CROWS 1664   // 13 row-tiles of 128 per cell chunk; 5 chunks cover 8320

typedef _Float16 f16x8 __attribute__((ext_vector_type(8)));
typedef _Float16 f16x4 __attribute__((ext_vector_type(4)));
typedef float f32x4 __attribute__((ext_vector_type(4)));

struct GemmSrc { const float* a[5]; };

__device__ __forceinline__ float bsum(float v){
  __shared__ float sh[4];
  __syncthreads();
  #pragma unroll
  for (int o=32;o;o>>=1) v += __shfl_down(v,o);
  if ((threadIdx.x & 63)==0) sh[threadIdx.x>>6] = v;
  __syncthreads();
  return sh[0]+sh[1]+sh[2]+sh[3];
}
__device__ __forceinline__ float bmaxr(float v){
  __shared__ float sh[4];
  __syncthreads();
  #pragma unroll
  for (int o=32;o;o>>=1) v = fmaxf(v,__shfl_down(v,o));
  if ((threadIdx.x & 63)==0) sh[threadIdx.x>>6] = v;
  __syncthreads();
  return fmaxf(fmaxf(sh[0],sh[1]),fmaxf(sh[2],sh[3]));
}
__device__ __forceinline__ float gelu_(float x){
  return 0.5f*x*(1.f+erff(x*0.70710678118654752f));
}

// ---------------- masks / augment ----------------
__global__ __launch_bounds__(256) void build_masks(
    const float* __restrict__ im, float* __restrict__ mk, float* __restrict__ sel,
    float* __restrict__ lastm, float* __restrict__ endm, float* __restrict__ ep,
    float* __restrict__ um, int* __restrict__ flag){
  int b = blockIdx.x, i = threadIdx.x;
  if (i < SS){
    float mye = (i<=1) ? 1.f : im[b*128 + (i-2)];
    float mne = (i==SS-1) ? 0.f : ((i==0) ? 1.f : im[b*128 + (i-1)]);
    float em  = mye - mne;
    float mns = (i==0) ? 0.f : mye;
    float lm;
    if (i < SS-1){
      int i1 = i+1;
      float mye1 = (i1<=1) ? 1.f : im[b*128 + (i1-2)];
      float mne1 = (i1==SS-1) ? 0.f : im[b*128 + (i1-1)];
      lm = mye1 - mne1;
    } else lm = 0.f;
    float sl = mns * mne * (1.f - lm);
    int idx = b*SS + i;
    mk[idx]=mye; sel[idx]=sl; lastm[idx]=lm; endm[idx]=em; ep[idx]=mye;
  } else if (i == SS) { um[b] = 1.f; }
  else if (i == SS+1 && b==0) { flag[0] = 0; }
}

__global__ __launch_bounds__(256) void build_seq(
    const float* __restrict__ seqin, const float* __restrict__ START,
    const float* __restrict__ END, const float* __restrict__ mk,
    const float* __restrict__ endm, float* __restrict__ out){
  int r = blockIdx.x; int b = r/SS, i = r%SS; int t = threadIdx.x;
  float em = endm[r], m = mk[r];
  #pragma unroll
  for (int q=0;q<4;q++){
    int j = t + q*256;
    float v;
    if (i==0) v = START[j];
    else if (i<=128) v = seqin[((size_t)b*128 + (i-1))*DD + j];
    else v = 0.f;
    v = em*END[j] + (1.f-em)*v;
    out[(size_t)r*DD + j] = v*m;
  }
}

// ---- weight transpose+convert: W[K][N] f32 -> WT hi/lo [N][K] f16 ----
// hi plane = f16(w*64); lo plane = f16((w*64 - hi)*2048). Both comfortably normal.
__global__ __launch_bounds__(256) void wtranspose(
    const float* __restrict__ W, _Float16* __restrict__ WTh, _Float16* __restrict__ WTl,
    int K, int N){
  __shared__ float Ts[32][33];
  int k0 = blockIdx.x*32, n0 = blockIdx.y*32;
  int t = threadIdx.x;
  int r = t>>3, c4 = (t&7)*4;
  float4 v = *(const float4*)(W + (size_t)(k0+r)*N + n0 + c4);
  Ts[r][c4]=v.x; Ts[r][c4+1]=v.y; Ts[r][c4+2]=v.z; Ts[r][c4+3]=v.w;
  __syncthreads();
  int n = t>>3, k4 = (t&7)*4;
  f16x4 h, lo;
  #pragma unroll
  for (int i=0;i<4;i++){
    float xs = Ts[k4+i][n] * 64.f;
    _Float16 hh = (_Float16)xs;
    h[i] = hh; lo[i] = (_Float16)((xs - (float)hh) * 2048.f);
  }
  *(f16x4*)(WTh + (size_t)(n0+n)*K + k0+k4) = h;
  *(f16x4*)(WTl + (size_t)(n0+n)*K + k0+k4) = lo;
}

// ---- MFMA GEMM: C[M,N] = gather-A[M,K](f32) @ W[K,N] via WT[N][K] f16 planes ----
// blockIdx.x = n-tile (128), blockIdx.y = m-tile (128). 256 thr = 4 waves (2x2).
// act: 0 store, 1 gelu+store, 2 gelu+fused scorer partial (spart width 16)
__global__ __launch_bounds__(256,2) void gemm_mfma(
    GemmSrc S, long lda,
    const _Float16* __restrict__ WTh, const _Float16* __restrict__ WTl,
    const float* __restrict__ bias,
    float* __restrict__ C, long ldc, int K, int act,
    const int* __restrict__ flag, float* __restrict__ spart, const float* __restrict__ Ws){
  if (flag[0]) return;
  __shared__ _Float16 Ah[128][40], Al[128][40];   // activations [m][k]
  __shared__ _Float16 Wh[128][40], Wl[128][40];   // W^T [n][k]
  const int t = threadIdx.x;
  const int wave = t >> 6, lane = t & 63;
  const int wm = wave >> 1, wn = wave & 1;
  const int l15 = lane & 15, l4 = lane >> 4;
  const long mb = (long)blockIdx.y * 128;
  const int  nb = blockIdx.x * 128;
  f32x4 accH[4][4], accX[4][4];
  #pragma unroll
  for (int i=0;i<4;i++)
    #pragma unroll
    for (int j=0;j<4;j++){ accH[i][j] = (f32x4){0.f,0.f,0.f,0.f}; accX[i][j] = (f32x4){0.f,0.f,0.f,0.f}; }

  for (int kt=0; kt<K; kt+=32){
    // stage activations f32 -> f16 hi + scaled lo
    #pragma unroll
    for (int p=0;p<4;p++){
      int f = t + 256*p;
      int m = f >> 3;
      int k4 = (f & 7) * 4;
      int kg = kt + k4;
      const float* src = S.a[kg >> 10];
      float4 v = *(const float4*)(src + (mb + m)*lda + (kg & 1023));
      f16x4 h, lo;
      _Float16 hh;
      hh=(_Float16)v.x; h[0]=hh; lo[0]=(_Float16)((v.x-(float)hh)*2048.f);
      hh=(_Float16)v.y; h[1]=hh; lo[1]=(_Float16)((v.y-(float)hh)*2048.f);
      hh=(_Float16)v.z; h[2]=hh; lo[2]=(_Float16)((v.z-(float)hh)*2048.f);
      hh=(_Float16)v.w; h[3]=hh; lo[3]=(_Float16)((v.w-(float)hh)*2048.f);
      *(f16x4*)&Ah[m][k4] = h;
      *(f16x4*)&Al[m][k4] = lo;
    }
    // stage W^T planes (already f16, k-contiguous)
    #pragma unroll
    for (int p=0;p<2;p++){
      int f = t + 256*p;
      int n = f >> 2;
      int ko = (f & 3) * 8;
      *(f16x8*)&Wh[n][ko] = *(const f16x8*)(WTh + (size_t)(nb + n)*K + kt + ko);
      *(f16x8*)&Wl[n][ko] = *(const f16x8*)(WTl + (size_t)(nb + n)*K + kt + ko);
    }
    __syncthreads();
    f16x8 wh[4], wl[4];
    #pragma unroll
    for (int i=0;i<4;i++){
      wh[i] = *(const f16x8*)&Wh[wn*64 + i*16 + l15][8*l4];
      wl[i] = *(const f16x8*)&Wl[wn*64 + i*16 + l15][8*l4];
    }
    #pragma unroll
    for (int mi=0;mi<4;mi++){
      f16x8 ahv = *(const f16x8*)&Ah[wm*64 + mi*16 + l15][8*l4];
      f16x8 alv = *(const f16x8*)&Al[wm*64 + mi*16 + l15][8*l4];
      #pragma unroll
      for (int ni=0;ni<4;ni++){
        accH[mi][ni] = __builtin_amdgcn_mfma_f32_16x16x32_f16(wh[ni], ahv, accH[mi][ni], 0,0,0);
        accX[mi][ni] = __builtin_amdgcn_mfma_f32_16x16x32_f16(wh[ni], alv, accX[mi][ni], 0,0,0);
        accX[mi][ni] = __builtin_amdgcn_mfma_f32_16x16x32_f16(wl[ni], ahv, accX[mi][ni], 0,0,0);
      }
    }
    __syncthreads();
  }

  const float IH = 1.f/64.f, IX = 1.f/131072.f;
  if (act==2){
    #pragma unroll
    for (int mi=0;mi<4;mi++){
      float s = 0.f;
      #pragma unroll
      for (int ni=0;ni<4;ni++){
        int nbase = nb + wn*64 + ni*16 + 4*l4;
        #pragma unroll
        for (int r=0;r<4;r++){
          float v = gelu_(accH[mi][ni][r]*IH + accX[mi][ni][r]*IX + bias[nbase+r]);
          s = fmaf(v, Ws[nbase+r], s);
        }
      }
      s += __shfl_xor(s, 16);
      s += __shfl_xor(s, 32);
      if (l4==0){
        long m = mb + wm*64 + mi*16 + l15;
        spart[m*16 + blockIdx.x*2 + wn] = s;
      }
    }
    return;
  }
  #pragma unroll
  for (int mi=0;mi<4;mi++){
    long m = mb + wm*64 + mi*16 + l15;
    #pragma unroll
    for (int ni=0;ni<4;ni++){
      int nbase = nb + wn*64 + ni*16 + 4*l4;
      float4 v;
      v.x = accH[mi][ni][0]*IH + accX[mi][ni][0]*IX + bias[nbase+0];
      v.y = accH[mi][ni][1]*IH + accX[mi][ni][1]*IX + bias[nbase+1];
      v.z = accH[mi][ni][2]*IH + accX[mi][ni][2]*IX + bias[nbase+2];
      v.w = accH[mi][ni][3]*IH + accX[mi][ni][3]*IX + bias[nbase+3];
      if (act==1){ v.x=gelu_(v.x); v.y=gelu_(v.y); v.z=gelu_(v.z); v.w=gelu_(v.w); }
      *(float4*)(C + m*ldc + nbase) = v;
    }
  }
}

// ---- f32 GEMM (fallback + init). act: 0 store, 1 gelu, 2 gelu+scorer (spart w=8) ----
__global__ __launch_bounds__(256,2) void gemm_f32(
    GemmSrc S, long lda, const float* __restrict__ B, const float* __restrict__ bias,
    float* __restrict__ C, long ldc, int N, int K, int act,
    const int* __restrict__ flag, float* __restrict__ spart, const float* __restrict__ Ws){
  if (flag[0]) return;
  __shared__ float Asm[16][132];
  __shared__ float Bsm[16][132];
  float acc[8][8];
  #pragma unroll
  for (int i=0;i<8;i++)
    #pragma unroll
    for (int j=0;j<8;j++) acc[i][j]=0.f;
  const int t = threadIdx.x;
  const int tx = t & 15, ty = t >> 4;
  const long mb = (long)blockIdx.y * 128;
  const int  nb = blockIdx.x * 128;
  for (int kt=0; kt<K; kt+=16){
    #pragma unroll
    for (int ii=0; ii<2; ii++){
      int f  = t + 256*ii;
      int m  = f >> 2;
      int k4 = (f & 3) * 4;
      int kg = kt + k4;
      const float* src = S.a[kg >> 10];
      float4 v = *(const float4*)(src + (mb + m)*lda + (kg & 1023));
      Asm[k4+0][m]=v.x; Asm[k4+1][m]=v.y; Asm[k4+2][m]=v.z; Asm[k4+3][m]=v.w;
    }
    #pragma unroll
    for (int ii=0; ii<2; ii++){
      int f  = t + 256*ii;
      int kk = f >> 5;
      int c4 = (f & 31)*4;
      *(float4*)&Bsm[kk][c4] = *(const float4*)(B + (long)(kt+kk)*N + nb + c4);
    }
    __syncthreads();
    #pragma unroll
    for (int kk=0;kk<16;kk++){
      float av[8], bv[8];
      *(float4*)&av[0] = *(const float4*)&Asm[kk][ty*4];
      *(float4*)&av[4] = *(const float4*)&Asm[kk][64+ty*4];
      *(float4*)&bv[0] = *(const float4*)&Bsm[kk][tx*4];
      *(float4*)&bv[4] = *(const float4*)&Bsm[kk][64+tx*4];
      #pragma unroll
      for (int r=0;r<8;r++)
        #pragma unroll
        for (int c=0;c<8;c++) acc[r][c] = fmaf(av[r],bv[c],acc[r][c]);
    }
    __syncthreads();
  }
  if (act==2){
    #pragma unroll
    for (int rh=0;rh<2;rh++)
    #pragma unroll
    for (int rr=0;rr<4;rr++){
      float s = 0.f;
      #pragma unroll
      for (int ch=0;ch<2;ch++){
        #pragma unroll
        for (int q=0;q<4;q++){
          int col = nb + ch*64 + tx*4 + q;
          float v = gelu_(acc[rh*4+rr][ch*4+q] + bias[col]);
          s = fmaf(v, Ws[col], s);
        }
      }
      s += __shfl_xor(s,1); s += __shfl_xor(s,2);
      s += __shfl_xor(s,4); s += __shfl_xor(s,8);
      if (tx==0) spart[(size_t)(mb + rh*64 + ty*4 + rr)*16 + blockIdx.x] = s;
    }
    return;
  }
  #pragma unroll
  for (int rh=0;rh<2;rh++)
  #pragma unroll
  for (int rr=0;rr<4;rr++){
    long row = mb + rh*64 + ty*4 + rr;
    #pragma unroll
    for (int ch=0;ch<2;ch++){
      int col = nb + ch*64 + tx*4;
      float t0 = acc[rh*4+rr][ch*4+0] + bias[col+0];
      float t1 = acc[rh*4+rr][ch*4+1] + bias[col+1];
      float t2 = acc[rh*4+rr][ch*4+2] + bias[col+2];
      float t3 = acc[rh*4+rr][ch*4+3] + bias[col+3];
      if (act==1){ t0=gelu_(t0); t1=gelu_(t1); t2=gelu_(t2); t3=gelu_(t3); }
      float4 v; v.x=t0; v.y=t1; v.z=t2; v.w=t3;
      *(float4*)(C + row*ldc + col) = v;
    }
  }
}

// ---- batched neighbor GEMM: Y[b] = P[b](130x130,pad132) @ X[b](130x1024) ----
__global__ __launch_bounds__(256,2) void bgemm(
    const float* __restrict__ P, const float* __restrict__ X, float* __restrict__ Y,
    const int* __restrict__ flag){
  if (flag[0]) return;
  __shared__ float Ps[64][17];
  __shared__ float Xs[16][132];
  const int t = threadIdx.x;
  const int nt = blockIdx.x, mt = blockIdx.y, b = blockIdx.z;
  const int i0 = mt*64;
  const float* Pb = P + (size_t)b*SS*LSTR;
  const float* Xb = X + (size_t)b*SS*DD + nt*128;
  float* Yb = Y + (size_t)b*SS*DD + nt*128;
  const int tx = t & 7, ty = t >> 3;
  float acc[2][16];
  #pragma unroll
  for (int r=0;r<2;r++)
    #pragma unroll
    for (int c=0;c<16;c++) acc[r][c]=0.f;
  for (int j0=0;j0<SS;j0+=16){
    { int r = t>>2, c0 = (t&3)*4;
      float4 v = make_float4(0.f,0.f,0.f,0.f);
      if (i0 + r < SS && j0 + c0 < LSTR) v = *(const float4*)(Pb + (size_t)(i0+r)*LSTR + j0 + c0);
      Ps[r][c0]=v.x; Ps[r][c0+1]=v.y; Ps[r][c0+2]=v.z; Ps[r][c0+3]=v.w;
    }
    #pragma unroll
    for (int ii=0;ii<2;ii++){
      int f = t + 256*ii;
      int jj = f>>5, c4 = (f&31)*4;
      float4 v = make_float4(0.f,0.f,0.f,0.f);
      if (j0 + jj < SS) v = *(const float4*)(Xb + (size_t)(j0+jj)*DD + c4);
      *(float4*)&Xs[jj][c4] = v;
    }
    __syncthreads();
    #pragma unroll
    for (int jj=0;jj<16;jj++){
      float p0 = Ps[2*ty][jj], p1 = Ps[2*ty+1][jj];
      #pragma unroll
      for (int q=0;q<4;q++){
        float4 xv = *(const float4*)&Xs[jj][tx*4 + 32*q];
        acc[0][q*4+0] = fmaf(p0,xv.x,acc[0][q*4+0]);
        acc[0][q*4+1] = fmaf(p0,xv.y,acc[0][q*4+1]);
        acc[0][q*4+2] = fmaf(p0,xv.z,acc[0][q*4+2]);
        acc[0][q*4+3] = fmaf(p0,xv.w,acc[0][q*4+3]);
        acc[1][q*4+0] = fmaf(p1,xv.x,acc[1][q*4+0]);
        acc[1][q*4+1] = fmaf(p1,xv.y,acc[1][q*4+1]);
        acc[1][q*4+2] = fmaf(p1,xv.z,acc[1][q*4+2]);
        acc[1][q*4+3] = fmaf(p1,xv.w,acc[1][q*4+3]);
      }
    }
    __syncthreads();
  }
  #pragma unroll
  for (int rr=0;rr<2;rr++){
    int row = i0 + 2*ty + rr;
    if (row < SS){
      #pragma unroll
      for (int q=0;q<4;q++){
        float4 v = make_float4(acc[rr][q*4],acc[rr][q*4+1],acc[rr][q*4+2],acc[rr][q*4+3]);
        *(float4*)(Yb + (size_t)row*DD + tx*4 + 32*q) = v;
      }
    }
  }
}

// ---------------- neighbor probabilities ----------------
__global__ void neighbor_kernel(const float* __restrict__ ep, const float* __restrict__ mk,
                                float* __restrict__ L, float* __restrict__ R,
                                const int* __restrict__ flag){
  if (flag[0]) return;
  int idx = blockIdx.x*blockDim.x + threadIdx.x;
  if (idx >= MM) return;
  int b = idx / SS, i = idx % SS;
  const float* p = ep + b*SS;
  const float* m = mk + b*SS;
  float* Lr = L + (size_t)idx*LSTR;
  float* Rr = R + (size_t)idx*LSTR;
  for (int j=0;j<LSTR;j++){ Lr[j]=0.f; Rr[j]=0.f; }
  float cs=0.f;
  for (int j=i+1;j<SS;j++){
    float mat = p[j]*m[j];
    cs += mat;
    float v = (cs>1.f) ? fmaxf(1.f-(cs-mat),0.f) : mat;
    Rr[j] = v*m[j];
  }
  cs=0.f;
  for (int j=i-1;j>=0;j--){
    float mat = p[j]*m[j];
    cs += mat;
    float v = (cs>1.f) ? fmaxf(1.f-(cs-mat),0.f) : mat;
    Lr[j] = v*m[j];
  }
}

// ---------------- LN after init ----------------
__global__ __launch_bounds__(256) void ln1_kernel(
    const float* __restrict__ xin, const float* __restrict__ g, const float* __restrict__ bb,
    const float* __restrict__ mk, float* __restrict__ out){
  int r = blockIdx.x, t = threadIdx.x;
  const float* xr = xin + (size_t)r*DD;
  float x[4]; float s=0.f;
  #pragma unroll
  for (int q=0;q<4;q++){ x[q]=xr[t+256*q]; s+=x[q]; }
  float mean = bsum(s)*(1.f/DD);
  float vs=0.f;
  #pragma unroll
  for (int q=0;q<4;q++){ float d=x[q]-mean; vs+=d*d; }
  float var = bsum(vs)*(1.f/DD);
  float inv = 1.f/sqrtf(var+1e-5f);
  float m = mk[r];
  #pragma unroll
  for (int q=0;q<4;q++){ int j=t+256*q; out[(size_t)r*DD+j] = ((x[q]-mean)*inv*g[j]+bb[j])*m; }
}

// ---------------- scorer finalize / max / tp ----------------
__global__ void scorer_final(const float* __restrict__ spart, const float* __restrict__ bs,
                             float* __restrict__ sc, const int* __restrict__ flag, int w){
  if (flag[0]) return;
  int r = blockIdx.x*blockDim.x + threadIdx.x;
  if (r >= MM) return;
  float s = bs[0];
  for (int k=0;k<w;k++) s += spart[(size_t)r*16+k];
  sc[r] = s;
}
__global__ __launch_bounds__(256) void max1(const float* __restrict__ sc, float* __restrict__ part,
                                            const int* __restrict__ flag){
  if (flag[0]) return;
  int idx = blockIdx.x*256 + threadIdx.x;
  float v = -1e30f;
  for (int i = idx; i < MM; i += 64*256) v = fmaxf(v, sc[i]);
  v = bmaxr(v);
  if (threadIdx.x==0) part[blockIdx.x] = v;
}
__global__ __launch_bounds__(64) void max2(const float* __restrict__ part, float* __restrict__ gm,
                                           const int* __restrict__ flag){
  if (flag[0]) return;
  float v = part[threadIdx.x];
  #pragma unroll
  for (int o=32;o;o>>=1) v = fmaxf(v, __shfl_down(v,o));
  if (threadIdx.x==0) gm[0] = fmaxf(v, 0.f);
}
__global__ void tp_kernel(const float* __restrict__ sc, const float* __restrict__ sel,
                          const float* __restrict__ um, const float* __restrict__ gm,
                          float* __restrict__ tp, const int* __restrict__ flag){
  if (flag[0]) return;
  int idx = blockIdx.x*blockDim.x + threadIdx.x;
  if (idx>=MM) return;
  int b = idx / SS;
  float g = gm[0];
  float et = expf(sc[idx]-g)*sel[idx];
  float en = expf(-g);
  tp[idx] = et/(et+en+2e-8f)*um[b];
}

// ---------------- gates + LN + blend (in-place sq), row-chunked ----------------
__global__ __launch_bounds__(256) void update_kernel(
    const float* __restrict__ cont, const float* __restrict__ l1, float* __restrict__ sq,
    const float* __restrict__ tp, const float* __restrict__ g, const float* __restrict__ bb,
    const int* __restrict__ flag, long row0){
  if (flag[0]) return;
  long r = row0 + blockIdx.x; int t = threadIdx.x;
  const float* cr = cont + (size_t)blockIdx.x*4096;
  const float* lr = l1 + (size_t)r*DD;
  float* sr = sq + (size_t)r*DD;
  float x[4], sv[4];
  float s=0.f;
  #pragma unroll
  for (int q=0;q<4;q++){
    int j = t+q*256;
    float c0=cr[j], c1=cr[DD+j], c2=cr[2*DD+j], c3=cr[3*DD+j];
    float g0=1.f/(1.f+expf(-c0));
    float g1=1.f/(1.f+expf(-c1));
    float g2=1.f/(1.f+expf(-c2));
    float lv=lr[j]; float sqv=sr[j]; sv[q]=sqv;
    x[q] = g0*lv + g1*sqv + g2*c3;
    s += x[q];
  }
  float mean = bsum(s)*(1.f/DD);
  float vs=0.f;
  #pragma unroll
  for (int q=0;q<4;q++){ float d=x[q]-mean; vs+=d*d; }
  float var = bsum(vs)*(1.f/DD);
  float inv = 1.f/sqrtf(var+1e-5f);
  float tpv = tp[r];
  #pragma unroll
  for (int q=0;q<4;q++){
    int j=t+q*256;
    float comp = (x[q]-mean)*inv*g[j]+bb[j];
    sr[j] = tpv*comp + (1.f-tpv)*sv[q];
  }
}

// ---------------- ep / active / done ----------------
__global__ void ep_update(float* __restrict__ ep, const float* __restrict__ R,
                          const float* __restrict__ tp, const int* __restrict__ flag){
  if (flag[0]) return;
  int idx = blockIdx.x*blockDim.x + threadIdx.x;
  if (idx>=MM) return;
  int b = idx / SS;
  const float* Rr = R + (size_t)idx*LSTR;
  const float* tb = tp + b*SS;
  float d=0.f;
  for (int j=0;j<SS;j++) d = fmaf(Rr[j],tb[j],d);
  ep[idx] *= (1.f - d);
}
__global__ __launch_bounds__(256) void active_um(const float* __restrict__ ep,
                                                 const float* __restrict__ sel,
                                                 float* __restrict__ um,
                                                 const int* __restrict__ flag){
  if (flag[0]) return;
  int b = blockIdx.x, t = threadIdx.x;
  float s = (t<SS) ? ep[b*SS+t]*sel[b*SS+t] : 0.f;
  s = bsum(s);
  if (t==0) um[b] *= (s >= 0.1f) ? 1.f : 0.f;
}
__global__ __launch_bounds__(64) void done_kernel(const float* __restrict__ um, int* __restrict__ flag){
  float v = um[threadIdx.x];
  unsigned long long b = __ballot(v > 0.f);
  if (threadIdx.x==0) flag[0] = (b==0ULL) ? 1 : 0;
}

// ---------------- outputs ----------------
__global__ __launch_bounds__(256) void output_kernel(const float* __restrict__ sq,
                                                     const float* __restrict__ mk,
                                                     float* __restrict__ out){
  int r = blockIdx.x; int b = r/SS, i = r%SS;
  if (i<1 || i>128) return;
  float m = mk[r]; int t=threadIdx.x;
  #pragma unroll
  for (int q=0;q<4;q++){
    int j = t+q*256;
    out[((size_t)b*128 + (i-1))*DD + j] = sq[(size_t)r*DD + j]*m;
  }
}
__global__ __launch_bounds__(256) void gstate_kernel(const float* __restrict__ sq,
                                                     const float* __restrict__ mk,
                                                     const float* __restrict__ lastm,
                                                     float* __restrict__ outg){
  int b = blockIdx.x; int t=threadIdx.x;
  #pragma unroll
  for (int q=0;q<4;q++){
    int j = t+q*256;
    float acc=0.f;
    for (int i=0;i<SS;i++){
      float w = lastm[b*SS+i]*mk[b*SS+i];
      acc = fmaf(w, sq[((size_t)(b*SS+i))*DD + j], acc);
    }
    outg[(size_t)b*DD + j] = acc;
  }
}

extern "C" void kernel_launch(void* const* d_in, const int* in_sizes, int n_in,
                              void* d_out, int out_size, void* d_ws, size_t ws_size,
                              hipStream_t stream) {
  const float* sequence   = (const float*)d_in[0];
  const float* input_mask = (const float*)d_in[1];
  const float* START      = (const float*)d_in[2];
  const float* END        = (const float*)d_in[3];
  const float* W_conv     = (const float*)d_in[4];
  const float* b_conv     = (const float*)d_in[5];
  const float* W_scorer   = (const float*)d_in[6];
  const float* b_scorer   = (const float*)d_in[7];
  const float* W_init     = (const float*)d_in[8];
  const float* b_init     = (const float*)d_in[9];
  const float* W_cell1    = (const float*)d_in[10];
  const float* b_cell1    = (const float*)d_in[11];
  const float* W_cell2    = (const float*)d_in[12];
  const float* b_cell2    = (const float*)d_in[13];
  const float* ln1g       = (const float*)d_in[14];
  const float* ln1b       = (const float*)d_in[15];
  const float* ln2g       = (const float*)d_in[16];
  const float* ln2b       = (const float*)d_in[17];

  float* ws = (float*)d_ws;
  const size_t U = (size_t)MM*DD;
  float* sq   = ws;
  float* l1   = ws + U;
  float* r1   = ws + 2*U;
  float* l2   = ws + 3*U;   // also hid-chunk
  float* r2   = ws + 4*U;   // also cont-chunk
  float* Lm   = ws + 5*U;
  float* Rm   = Lm + (size_t)NB*SS*LSTR;
  float* maskv= Rm + (size_t)NB*SS*LSTR;
  float* sel  = maskv + MM;
  float* lastm= sel + MM;
  float* endm = lastm + MM;
  float* ep   = endm + MM;
  float* scb  = ep + MM;
  float* tpb  = scb + MM;
  float* spart= tpb + MM;          // MM*16
  float* umb  = spart + (size_t)MM*16;
  float* part = umb + NB;
  float* gmx  = part + 64;
  int*   flag = (int*)(gmx + 4);
  // f16 W^T planes region (MFMA mode)
  size_t used_floats = (size_t)((float*)(flag+4) - ws);
  used_floats = (used_floats + 7) & ~(size_t)7;
  _Float16* WTc_h = (_Float16*)(ws + used_floats);
  const size_t SC = (size_t)1024*5120, S1 = (size_t)4096*2048, S2 = (size_t)4096*4096;
  _Float16* WTc_l = WTc_h + SC;
  _Float16* WT1_h = WTc_l + SC;
  _Float16* WT1_l = WT1_h + S1;
  _Float16* WT2_h = WT1_l + S1;
  _Float16* WT2_l = WT2_h + S2;
  size_t need_bytes = (size_t)((char*)(WT2_l + S2) - (char*)d_ws);
  const bool use_mfma = ws_size >= need_bytes;

  build_masks<<<NB,256,0,stream>>>(input_mask, maskv, sel, lastm, endm, ep, umb, flag);
  build_seq<<<MM,256,0,stream>>>(sequence, START, END, maskv, endm, r1);
  GemmSrc si; si.a[0]=r1; si.a[1]=r1; si.a[2]=r1; si.a[3]=r1; si.a[4]=r1;
  gemm_f32<<<dim3(8,65),256,0,stream>>>(si, DD, W_init, b_init, l2, DD, DD, DD, 0, flag, nullptr, nullptr);
  ln1_kernel<<<MM,256,0,stream>>>(l2, ln1g, ln1b, maskv, sq);

  if (use_mfma){
    wtranspose<<<dim3(160,32),256,0,stream>>>(W_conv,  WTc_h, WTc_l, 5120, 1024);
    wtranspose<<<dim3(64,128),256,0,stream>>>(W_cell1, WT1_h, WT1_l, 2048, 4096);
    wtranspose<<<dim3(128,128),256,0,stream>>>(W_cell2, WT2_h, WT2_l, 4096, 4096);
  }

  for (int it=0; it<25; ++it){
    neighbor_kernel<<<(MM+255)/256,256,0,stream>>>(ep, maskv, Lm, Rm, flag);
    bgemm<<<dim3(8,3,NB),256,0,stream>>>(Lm, sq, l1, flag);
    bgemm<<<dim3(8,3,NB),256,0,stream>>>(Rm, sq, r1, flag);
    bgemm<<<dim3(8,3,NB),256,0,stream>>>(Lm, l1, l2, flag);
    bgemm<<<dim3(8,3,NB),256,0,stream>>>(Rm, r1, r2, flag);
    GemmSrc s5; s5.a[0]=l2; s5.a[1]=l1; s5.a[2]=sq; s5.a[3]=r1; s5.a[4]=r2;
    if (use_mfma){
      gemm_mfma<<<dim3(8,65),256,0,stream>>>(s5, DD, WTc_h, WTc_l, b_conv, nullptr, 0, 5120, 2, flag, spart, W_scorer);
      scorer_final<<<(MM+255)/256,256,0,stream>>>(spart, b_scorer, scb, flag, 16);
    } else {
      gemm_f32<<<dim3(8,65),256,0,stream>>>(s5, DD, W_conv, b_conv, nullptr, DD, DD, 5*DD, 2, flag, spart, W_scorer);
      scorer_final<<<(MM+255)/256,256,0,stream>>>(spart, b_scorer, scb, flag, 8);
    }
    max1<<<64,256,0,stream>>>(scb, part, flag);
    max2<<<1,64,0,stream>>>(part, gmx, flag);
    tp_kernel<<<(MM+255)/256,256,0,stream>>>(scb, sel, umb, gmx, tpb, flag);
    for (int c=0;c<5;c++){
      long row0 = (long)c*CROWS;
      GemmSrc s2; s2.a[0]=l1+row0*DD; s2.a[1]=sq+row0*DD; s2.a[2]=s2.a[1]; s2.a[3]=s2.a[1]; s2.a[4]=s2.a[1];
      GemmSrc s3; s3.a[0]=l2; s3.a[1]=l2+DD; s3.a[2]=l2+2*DD; s3.a[3]=l2+3*DD; s3.a[4]=l2;
      if (use_mfma){
        gemm_mfma<<<dim3(32,13),256,0,stream>>>(s2, DD, WT1_h, WT1_l, b_cell1, l2, 4096, 2048, 1, flag, nullptr, nullptr);
        gemm_mfma<<<dim3(32,13),256,0,stream>>>(s3, 4096, WT2_h, WT2_l, b_cell2, r2, 4096, 4096, 0, flag, nullptr, nullptr);
      } else {
        gemm_f32<<<dim3(32,13),256,0,stream>>>(s2, DD, W_cell1, b_cell1, l2, 4096, 4096, 2048, 1, flag, nullptr, nullptr);
        gemm_f32<<<dim3(32,13),256,0,stream>>>(s3, 4096, W_cell2, b_cell2, r2, 4096, 4096, 4096, 0, flag, nullptr, nullptr);
      }
      update_kernel<<<CROWS,256,0,stream>>>(r2, l1, sq, tpb, ln2g, ln2b, flag, row0);
    }
    ep_update<<<(MM+255)/256,256,0,stream>>>(ep, Rm, tpb, flag);
    active_um<<<NB,256,0,stream>>>(ep, sel, umb, flag);
    done_kernel<<<1,64,0,stream>>>(umb, flag);
  }

  float* out = (float*)d_out;
  output_kernel<<<MM,256,0,stream>>>(sq, maskv, out);
  gstate_kernel<<<NB,256,0,stream>>>(sq, maskv, lastm, out + (size_t)NB*128*DD);
}

// Round 5
// 68643.066 us; speedup vs baseline: 2.6875x; 2.6424x over previous
//
#include <hip/hip_runtime.h>
#include <math.h>

// CRvNN forward. N=64, S=130 (augmented), D=1024, 25 steps.
// f32 everywhere except the 3 big GEMMs: f16 hi/lo split MFMA with renormalized
// planes (W x64, lo x2048):  D = (Wh*Ah)/64 + (Wh*Al + Wl*Ah)/131072.
// W tiles are transposed+split IN-KERNEL from the original f32 W[K][N] (no
// persistent planes needed -> fits the ~180MB workspace). If ws_size is large
// enough, persistent W^T f16 planes are used instead (template<PRE>).
// Workspace (floats), U = 8320*1024:
//  sq[0,U) | l1[U,2U) | r1[2U,3U) | l2[3U,4U) | r2[4U,5U)
//  l2/r2 double as hid-chunk/cont-chunk during the cell pipeline.
//  Tail: Lm/Rm, masks, sc/tp, spart(MM*16), um/part/gmx/flag.

#define NB 64
#define SS 130
#define DD 1024
#define MM (NB*SS)
#define LSTR 132
#define CROWS 1664   // 13 row-tiles of 128 per cell chunk; 5 chunks cover 8320

typedef _Float16 f16x8 __attribute__((ext_vector_type(8)));
typedef _Float16 f16x4 __attribute__((ext_vector_type(4)));
typedef _Float16 f16x2 __attribute__((ext_vector_type(2)));
typedef float f32x4 __attribute__((ext_vector_type(4)));

struct GemmSrc { const float* a[5]; };

__device__ __forceinline__ float bsum(float v){
  __shared__ float sh[4];
  __syncthreads();
  #pragma unroll
  for (int o=32;o;o>>=1) v += __shfl_down(v,o);
  if ((threadIdx.x & 63)==0) sh[threadIdx.x>>6] = v;
  __syncthreads();
  return sh[0]+sh[1]+sh[2]+sh[3];
}
__device__ __forceinline__ float bmaxr(float v){
  __shared__ float sh[4];
  __syncthreads();
  #pragma unroll
  for (int o=32;o;o>>=1) v = fmaxf(v,__shfl_down(v,o));
  if ((threadIdx.x & 63)==0) sh[threadIdx.x>>6] = v;
  __syncthreads();
  return fmaxf(fmaxf(sh[0],sh[1]),fmaxf(sh[2],sh[3]));
}
__device__ __forceinline__ float gelu_(float x){
  return 0.5f*x*(1.f+erff(x*0.70710678118654752f));
}

// ---------------- masks / augment ----------------
__global__ __launch_bounds__(256) void build_masks(
    const float* __restrict__ im, float* __restrict__ mk, float* __restrict__ sel,
    float* __restrict__ lastm, float* __restrict__ endm, float* __restrict__ ep,
    float* __restrict__ um, int* __restrict__ flag){
  int b = blockIdx.x, i = threadIdx.x;
  if (i < SS){
    float mye = (i<=1) ? 1.f : im[b*128 + (i-2)];
    float mne = (i==SS-1) ? 0.f : ((i==0) ? 1.f : im[b*128 + (i-1)]);
    float em  = mye - mne;
    float mns = (i==0) ? 0.f : mye;
    float lm;
    if (i < SS-1){
      int i1 = i+1;
      float mye1 = (i1<=1) ? 1.f : im[b*128 + (i1-2)];
      float mne1 = (i1==SS-1) ? 0.f : im[b*128 + (i1-1)];
      lm = mye1 - mne1;
    } else lm = 0.f;
    float sl = mns * mne * (1.f - lm);
    int idx = b*SS + i;
    mk[idx]=mye; sel[idx]=sl; lastm[idx]=lm; endm[idx]=em; ep[idx]=mye;
  } else if (i == SS) { um[b] = 1.f; }
  else if (i == SS+1 && b==0) { flag[0] = 0; }
}

__global__ __launch_bounds__(256) void build_seq(
    const float* __restrict__ seqin, const float* __restrict__ START,
    const float* __restrict__ END, const float* __restrict__ mk,
    const float* __restrict__ endm, float* __restrict__ out){
  int r = blockIdx.x; int b = r/SS, i = r%SS; int t = threadIdx.x;
  float em = endm[r], m = mk[r];
  #pragma unroll
  for (int q=0;q<4;q++){
    int j = t + q*256;
    float v;
    if (i==0) v = START[j];
    else if (i<=128) v = seqin[((size_t)b*128 + (i-1))*DD + j];
    else v = 0.f;
    v = em*END[j] + (1.f-em)*v;
    out[(size_t)r*DD + j] = v*m;
  }
}

// ---- weight transpose+convert (PRE tier): W[K][N] f32 -> WT hi/lo [N][K] f16 ----
__global__ __launch_bounds__(256) void wtranspose(
    const float* __restrict__ W, _Float16* __restrict__ WTh, _Float16* __restrict__ WTl,
    int K, int N){
  __shared__ float Ts[32][33];
  int k0 = blockIdx.x*32, n0 = blockIdx.y*32;
  int t = threadIdx.x;
  int r = t>>3, c4 = (t&7)*4;
  float4 v = *(const float4*)(W + (size_t)(k0+r)*N + n0 + c4);
  Ts[r][c4]=v.x; Ts[r][c4+1]=v.y; Ts[r][c4+2]=v.z; Ts[r][c4+3]=v.w;
  __syncthreads();
  int n = t>>3, k4 = (t&7)*4;
  f16x4 h, lo;
  #pragma unroll
  for (int i=0;i<4;i++){
    float xs = Ts[k4+i][n] * 64.f;
    _Float16 hh = (_Float16)xs;
    h[i] = hh; lo[i] = (_Float16)((xs - (float)hh) * 2048.f);
  }
  *(f16x4*)(WTh + (size_t)(n0+n)*K + k0+k4) = h;
  *(f16x4*)(WTl + (size_t)(n0+n)*K + k0+k4) = lo;
}

// ---- MFMA GEMM: C[M,N] = gather-A[M,K](f32) @ W[K,N] via f16 hi/lo planes ----
// PRE: W planes preconverted [N][K]. !PRE: transpose+split W f32[K][N] in-kernel.
// blockIdx.x = n-tile (128), blockIdx.y = m-tile (128). 256 thr = 4 waves (2x2).
// act: 0 store, 1 gelu+store, 2 gelu+fused scorer partial (spart width 16)
template<bool PRE>
__global__ __launch_bounds__(256,2) void gemm_mfma(
    GemmSrc S, long lda,
    const _Float16* __restrict__ WTh, const _Float16* __restrict__ WTl,
    const float* __restrict__ Wf, int Nw,
    const float* __restrict__ bias,
    float* __restrict__ C, long ldc, int K, int act,
    const int* __restrict__ flag, float* __restrict__ spart, const float* __restrict__ Ws){
  if (flag[0]) return;
  __shared__ _Float16 Ah[128][40], Al[128][40];   // activations [m][k]
  __shared__ _Float16 Wh[128][40], Wl[128][40];   // W^T [n][k]
  const int t = threadIdx.x;
  const int wave = t >> 6, lane = t & 63;
  const int wm = wave >> 1, wn = wave & 1;
  const int l15 = lane & 15, l4 = lane >> 4;
  const long mb = (long)blockIdx.y * 128;
  const int  nb = blockIdx.x * 128;
  f32x4 accH[4][4], accX[4][4];
  #pragma unroll
  for (int i=0;i<4;i++)
    #pragma unroll
    for (int j=0;j<4;j++){ accH[i][j] = (f32x4){0.f,0.f,0.f,0.f}; accX[i][j] = (f32x4){0.f,0.f,0.f,0.f}; }

  for (int kt=0; kt<K; kt+=32){
    // stage activations f32 -> f16 hi + scaled lo
    #pragma unroll
    for (int p=0;p<4;p++){
      int f = t + 256*p;
      int m = f >> 3;
      int k4 = (f & 7) * 4;
      int kg = kt + k4;
      const float* src = S.a[kg >> 10];
      float4 v = *(const float4*)(src + (mb + m)*lda + (kg & 1023));
      f16x4 h, lo;
      _Float16 hh;
      hh=(_Float16)v.x; h[0]=hh; lo[0]=(_Float16)((v.x-(float)hh)*2048.f);
      hh=(_Float16)v.y; h[1]=hh; lo[1]=(_Float16)((v.y-(float)hh)*2048.f);
      hh=(_Float16)v.z; h[2]=hh; lo[2]=(_Float16)((v.z-(float)hh)*2048.f);
      hh=(_Float16)v.w; h[3]=hh; lo[3]=(_Float16)((v.w-(float)hh)*2048.f);
      *(f16x4*)&Ah[m][k4] = h;
      *(f16x4*)&Al[m][k4] = lo;
    }
    if constexpr (PRE){
      // stage preconverted W^T planes (k-contiguous)
      #pragma unroll
      for (int p=0;p<2;p++){
        int f = t + 256*p;
        int n = f >> 2;
        int ko = (f & 3) * 8;
        *(f16x8*)&Wh[n][ko] = *(const f16x8*)(WTh + (size_t)(nb + n)*K + kt + ko);
        *(f16x8*)&Wl[n][ko] = *(const f16x8*)(WTl + (size_t)(nb + n)*K + kt + ko);
      }
    } else {
      // transpose + hi/lo split from f32 W[K][N]; coalesced loads along n,
      // n-stride-32 write assignment keeps LDS write conflicts ~4-way.
      #pragma unroll
      for (int p=0;p<2;p++){
        int u = t + 256*p;
        int kp = u >> 5;          // k-pair: rows kt+2kp, kt+2kp+1
        int c  = u & 31;          // column group: n = c + 32*i
        const float* wsrc = Wf + (size_t)(kt + 2*kp)*Nw + nb + c;
        #pragma unroll
        for (int i=0;i<4;i++){
          float x0 = wsrc[32*i] * 64.f;
          float x1 = wsrc[(size_t)Nw + 32*i] * 64.f;
          _Float16 h0 = (_Float16)x0, h1 = (_Float16)x1;
          _Float16 g0 = (_Float16)((x0 - (float)h0)*2048.f);
          _Float16 g1 = (_Float16)((x1 - (float)h1)*2048.f);
          f16x2 hp; hp[0]=h0; hp[1]=h1;
          f16x2 lp; lp[0]=g0; lp[1]=g1;
          int n = c + 32*i;
          *(f16x2*)&Wh[n][2*kp] = hp;
          *(f16x2*)&Wl[n][2*kp] = lp;
        }
      }
    }
    __syncthreads();
    f16x8 wh[4], wl[4];
    #pragma unroll
    for (int i=0;i<4;i++){
      wh[i] = *(const f16x8*)&Wh[wn*64 + i*16 + l15][8*l4];
      wl[i] = *(const f16x8*)&Wl[wn*64 + i*16 + l15][8*l4];
    }
    #pragma unroll
    for (int mi=0;mi<4;mi++){
      f16x8 ahv = *(const f16x8*)&Ah[wm*64 + mi*16 + l15][8*l4];
      f16x8 alv = *(const f16x8*)&Al[wm*64 + mi*16 + l15][8*l4];
      #pragma unroll
      for (int ni=0;ni<4;ni++){
        accH[mi][ni] = __builtin_amdgcn_mfma_f32_16x16x32_f16(wh[ni], ahv, accH[mi][ni], 0,0,0);
        accX[mi][ni] = __builtin_amdgcn_mfma_f32_16x16x32_f16(wh[ni], alv, accX[mi][ni], 0,0,0);
        accX[mi][ni] = __builtin_amdgcn_mfma_f32_16x16x32_f16(wl[ni], ahv, accX[mi][ni], 0,0,0);
      }
    }
    __syncthreads();
  }

  const float IH = 1.f/64.f, IX = 1.f/131072.f;
  if (act==2){
    #pragma unroll
    for (int mi=0;mi<4;mi++){
      float s = 0.f;
      #pragma unroll
      for (int ni=0;ni<4;ni++){
        int nbase = nb + wn*64 + ni*16 + 4*l4;
        #pragma unroll
        for (int r=0;r<4;r++){
          float v = gelu_(accH[mi][ni][r]*IH + accX[mi][ni][r]*IX + bias[nbase+r]);
          s = fmaf(v, Ws[nbase+r], s);
        }
      }
      s += __shfl_xor(s, 16);
      s += __shfl_xor(s, 32);
      if (l4==0){
        long m = mb + wm*64 + mi*16 + l15;
        spart[m*16 + blockIdx.x*2 + wn] = s;
      }
    }
    return;
  }
  #pragma unroll
  for (int mi=0;mi<4;mi++){
    long m = mb + wm*64 + mi*16 + l15;
    #pragma unroll
    for (int ni=0;ni<4;ni++){
      int nbase = nb + wn*64 + ni*16 + 4*l4;
      float4 v;
      v.x = accH[mi][ni][0]*IH + accX[mi][ni][0]*IX + bias[nbase+0];
      v.y = accH[mi][ni][1]*IH + accX[mi][ni][1]*IX + bias[nbase+1];
      v.z = accH[mi][ni][2]*IH + accX[mi][ni][2]*IX + bias[nbase+2];
      v.w = accH[mi][ni][3]*IH + accX[mi][ni][3]*IX + bias[nbase+3];
      if (act==1){ v.x=gelu_(v.x); v.y=gelu_(v.y); v.z=gelu_(v.z); v.w=gelu_(v.w); }
      *(float4*)(C + m*ldc + nbase) = v;
    }
  }
}

// ---- f32 GEMM (init only) ----
__global__ __launch_bounds__(256,2) void gemm_f32(
    GemmSrc S, long lda, const float* __restrict__ B, const float* __restrict__ bias,
    float* __restrict__ C, long ldc, int N, int K, int act,
    const int* __restrict__ flag){
  if (flag[0]) return;
  __shared__ float Asm[16][132];
  __shared__ float Bsm[16][132];
  float acc[8][8];
  #pragma unroll
  for (int i=0;i<8;i++)
    #pragma unroll
    for (int j=0;j<8;j++) acc[i][j]=0.f;
  const int t = threadIdx.x;
  const int tx = t & 15, ty = t >> 4;
  const long mb = (long)blockIdx.y * 128;
  const int  nb = blockIdx.x * 128;
  for (int kt=0; kt<K; kt+=16){
    #pragma unroll
    for (int ii=0; ii<2; ii++){
      int f  = t + 256*ii;
      int m  = f >> 2;
      int k4 = (f & 3) * 4;
      int kg = kt + k4;
      const float* src = S.a[kg >> 10];
      float4 v = *(const float4*)(src + (mb + m)*lda + (kg & 1023));
      Asm[k4+0][m]=v.x; Asm[k4+1][m]=v.y; Asm[k4+2][m]=v.z; Asm[k4+3][m]=v.w;
    }
    #pragma unroll
    for (int ii=0; ii<2; ii++){
      int f  = t + 256*ii;
      int kk = f >> 5;
      int c4 = (f & 31)*4;
      *(float4*)&Bsm[kk][c4] = *(const float4*)(B + (long)(kt+kk)*N + nb + c4);
    }
    __syncthreads();
    #pragma unroll
    for (int kk=0;kk<16;kk++){
      float av[8], bv[8];
      *(float4*)&av[0] = *(const float4*)&Asm[kk][ty*4];
      *(float4*)&av[4] = *(const float4*)&Asm[kk][64+ty*4];
      *(float4*)&bv[0] = *(const float4*)&Bsm[kk][tx*4];
      *(float4*)&bv[4] = *(const float4*)&Bsm[kk][64+tx*4];
      #pragma unroll
      for (int r=0;r<8;r++)
        #pragma unroll
        for (int c=0;c<8;c++) acc[r][c] = fmaf(av[r],bv[c],acc[r][c]);
    }
    __syncthreads();
  }
  #pragma unroll
  for (int rh=0;rh<2;rh++)
  #pragma unroll
  for (int rr=0;rr<4;rr++){
    long row = mb + rh*64 + ty*4 + rr;
    #pragma unroll
    for (int ch=0;ch<2;ch++){
      int col = nb + ch*64 + tx*4;
      float t0 = acc[rh*4+rr][ch*4+0] + bias[col+0];
      float t1 = acc[rh*4+rr][ch*4+1] + bias[col+1];
      float t2 = acc[rh*4+rr][ch*4+2] + bias[col+2];
      float t3 = acc[rh*4+rr][ch*4+3] + bias[col+3];
      if (act==1){ t0=gelu_(t0); t1=gelu_(t1); t2=gelu_(t2); t3=gelu_(t3); }
      float4 v; v.x=t0; v.y=t1; v.z=t2; v.w=t3;
      *(float4*)(C + row*ldc + col) = v;
    }
  }
}

// ---- batched neighbor GEMM: Y[b] = P[b](130x130,pad132) @ X[b](130x1024) ----
__global__ __launch_bounds__(256,2) void bgemm(
    const float* __restrict__ P, const float* __restrict__ X, float* __restrict__ Y,
    const int* __restrict__ flag){
  if (flag[0]) return;
  __shared__ float Ps[64][17];
  __shared__ float Xs[16][132];
  const int t = threadIdx.x;
  const int nt = blockIdx.x, mt = blockIdx.y, b = blockIdx.z;
  const int i0 = mt*64;
  const float* Pb = P + (size_t)b*SS*LSTR;
  const float* Xb = X + (size_t)b*SS*DD + nt*128;
  float* Yb = Y + (size_t)b*SS*DD + nt*128;
  const int tx = t & 7, ty = t >> 3;
  float acc[2][16];
  #pragma unroll
  for (int r=0;r<2;r++)
    #pragma unroll
    for (int c=0;c<16;c++) acc[r][c]=0.f;
  for (int j0=0;j0<SS;j0+=16){
    { int r = t>>2, c0 = (t&3)*4;
      float4 v = make_float4(0.f,0.f,0.f,0.f);
      if (i0 + r < SS && j0 + c0 < LSTR) v = *(const float4*)(Pb + (size_t)(i0+r)*LSTR + j0 + c0);
      Ps[r][c0]=v.x; Ps[r][c0+1]=v.y; Ps[r][c0+2]=v.z; Ps[r][c0+3]=v.w;
    }
    #pragma unroll
    for (int ii=0;ii<2;ii++){
      int f = t + 256*ii;
      int jj = f>>5, c4 = (f&31)*4;
      float4 v = make_float4(0.f,0.f,0.f,0.f);
      if (j0 + jj < SS) v = *(const float4*)(Xb + (size_t)(j0+jj)*DD + c4);
      *(float4*)&Xs[jj][c4] = v;
    }
    __syncthreads();
    #pragma unroll
    for (int jj=0;jj<16;jj++){
      float p0 = Ps[2*ty][jj], p1 = Ps[2*ty+1][jj];
      #pragma unroll
      for (int q=0;q<4;q++){
        float4 xv = *(const float4*)&Xs[jj][tx*4 + 32*q];
        acc[0][q*4+0] = fmaf(p0,xv.x,acc[0][q*4+0]);
        acc[0][q*4+1] = fmaf(p0,xv.y,acc[0][q*4+1]);
        acc[0][q*4+2] = fmaf(p0,xv.z,acc[0][q*4+2]);
        acc[0][q*4+3] = fmaf(p0,xv.w,acc[0][q*4+3]);
        acc[1][q*4+0] = fmaf(p1,xv.x,acc[1][q*4+0]);
        acc[1][q*4+1] = fmaf(p1,xv.y,acc[1][q*4+1]);
        acc[1][q*4+2] = fmaf(p1,xv.z,acc[1][q*4+2]);
        acc[1][q*4+3] = fmaf(p1,xv.w,acc[1][q*4+3]);
      }
    }
    __syncthreads();
  }
  #pragma unroll
  for (int rr=0;rr<2;rr++){
    int row = i0 + 2*ty + rr;
    if (row < SS){
      #pragma unroll
      for (int q=0;q<4;q++){
        float4 v = make_float4(acc[rr][q*4],acc[rr][q*4+1],acc[rr][q*4+2],acc[rr][q*4+3]);
        *(float4*)(Yb + (size_t)row*DD + tx*4 + 32*q) = v;
      }
    }
  }
}

// ---------------- neighbor probabilities ----------------
__global__ void neighbor_kernel(const float* __restrict__ ep, const float* __restrict__ mk,
                                float* __restrict__ L, float* __restrict__ R,
                                const int* __restrict__ flag){
  if (flag[0]) return;
  int idx = blockIdx.x*blockDim.x + threadIdx.x;
  if (idx >= MM) return;
  int b = idx / SS, i = idx % SS;
  const float* p = ep + b*SS;
  const float* m = mk + b*SS;
  float* Lr = L + (size_t)idx*LSTR;
  float* Rr = R + (size_t)idx*LSTR;
  for (int j=0;j<LSTR;j++){ Lr[j]=0.f; Rr[j]=0.f; }
  float cs=0.f;
  for (int j=i+1;j<SS;j++){
    float mat = p[j]*m[j];
    cs += mat;
    float v = (cs>1.f) ? fmaxf(1.f-(cs-mat),0.f) : mat;
    Rr[j] = v*m[j];
  }
  cs=0.f;
  for (int j=i-1;j>=0;j--){
    float mat = p[j]*m[j];
    cs += mat;
    float v = (cs>1.f) ? fmaxf(1.f-(cs-mat),0.f) : mat;
    Lr[j] = v*m[j];
  }
}

// ---------------- LN after init ----------------
__global__ __launch_bounds__(256) void ln1_kernel(
    const float* __restrict__ xin, const float* __restrict__ g, const float* __restrict__ bb,
    const float* __restrict__ mk, float* __restrict__ out){
  int r = blockIdx.x, t = threadIdx.x;
  const float* xr = xin + (size_t)r*DD;
  float x[4]; float s=0.f;
  #pragma unroll
  for (int q=0;q<4;q++){ x[q]=xr[t+256*q]; s+=x[q]; }
  float mean = bsum(s)*(1.f/DD);
  float vs=0.f;
  #pragma unroll
  for (int q=0;q<4;q++){ float d=x[q]-mean; vs+=d*d; }
  float var = bsum(vs)*(1.f/DD);
  float inv = 1.f/sqrtf(var+1e-5f);
  float m = mk[r];
  #pragma unroll
  for (int q=0;q<4;q++){ int j=t+256*q; out[(size_t)r*DD+j] = ((x[q]-mean)*inv*g[j]+bb[j])*m; }
}

// ---------------- scorer finalize / max / tp ----------------
__global__ void scorer_final(const float* __restrict__ spart, const float* __restrict__ bs,
                             float* __restrict__ sc, const int* __restrict__ flag){
  if (flag[0]) return;
  int r = blockIdx.x*blockDim.x + threadIdx.x;
  if (r >= MM) return;
  float s = bs[0];
  #pragma unroll
  for (int k=0;k<16;k++) s += spart[(size_t)r*16+k];
  sc[r] = s;
}
__global__ __launch_bounds__(256) void max1(const float* __restrict__ sc, float* __restrict__ part,
                                            const int* __restrict__ flag){
  if (flag[0]) return;
  int idx = blockIdx.x*256 + threadIdx.x;
  float v = -1e30f;
  for (int i = idx; i < MM; i += 64*256) v = fmaxf(v, sc[i]);
  v = bmaxr(v);
  if (threadIdx.x==0) part[blockIdx.x] = v;
}
__global__ __launch_bounds__(64) void max2(const float* __restrict__ part, float* __restrict__ gm,
                                           const int* __restrict__ flag){
  if (flag[0]) return;
  float v = part[threadIdx.x];
  #pragma unroll
  for (int o=32;o;o>>=1) v = fmaxf(v, __shfl_down(v,o));
  if (threadIdx.x==0) gm[0] = fmaxf(v, 0.f);
}
__global__ void tp_kernel(const float* __restrict__ sc, const float* __restrict__ sel,
                          const float* __restrict__ um, const float* __restrict__ gm,
                          float* __restrict__ tp, const int* __restrict__ flag){
  if (flag[0]) return;
  int idx = blockIdx.x*blockDim.x + threadIdx.x;
  if (idx>=MM) return;
  int b = idx / SS;
  float g = gm[0];
  float et = expf(sc[idx]-g)*sel[idx];
  float en = expf(-g);
  tp[idx] = et/(et+en+2e-8f)*um[b];
}

// ---------------- gates + LN + blend (in-place sq), row-chunked ----------------
__global__ __launch_bounds__(256) void update_kernel(
    const float* __restrict__ cont, const float* __restrict__ l1, float* __restrict__ sq,
    const float* __restrict__ tp, const float* __restrict__ g, const float* __restrict__ bb,
    const int* __restrict__ flag, long row0){
  if (flag[0]) return;
  long r = row0 + blockIdx.x; int t = threadIdx.x;
  const float* cr = cont + (size_t)blockIdx.x*4096;
  const float* lr = l1 + (size_t)r*DD;
  float* sr = sq + (size_t)r*DD;
  float x[4], sv[4];
  float s=0.f;
  #pragma unroll
  for (int q=0;q<4;q++){
    int j = t+q*256;
    float c0=cr[j], c1=cr[DD+j], c2=cr[2*DD+j], c3=cr[3*DD+j];
    float g0=1.f/(1.f+expf(-c0));
    float g1=1.f/(1.f+expf(-c1));
    float g2=1.f/(1.f+expf(-c2));
    float lv=lr[j]; float sqv=sr[j]; sv[q]=sqv;
    x[q] = g0*lv + g1*sqv + g2*c3;
    s += x[q];
  }
  float mean = bsum(s)*(1.f/DD);
  float vs=0.f;
  #pragma unroll
  for (int q=0;q<4;q++){ float d=x[q]-mean; vs+=d*d; }
  float var = bsum(vs)*(1.f/DD);
  float inv = 1.f/sqrtf(var+1e-5f);
  float tpv = tp[r];
  #pragma unroll
  for (int q=0;q<4;q++){
    int j=t+q*256;
    float comp = (x[q]-mean)*inv*g[j]+bb[j];
    sr[j] = tpv*comp + (1.f-tpv)*sv[q];
  }
}

// ---------------- ep / active / done ----------------
__global__ void ep_update(float* __restrict__ ep, const float* __restrict__ R,
                          const float* __restrict__ tp, const int* __restrict__ flag){
  if (flag[0]) return;
  int idx = blockIdx.x*blockDim.x + threadIdx.x;
  if (idx>=MM) return;
  int b = idx / SS;
  const float* Rr = R + (size_t)idx*LSTR;
  const float* tb = tp + b*SS;
  float d=0.f;
  for (int j=0;j<SS;j++) d = fmaf(Rr[j],tb[j],d);
  ep[idx] *= (1.f - d);
}
__global__ __launch_bounds__(256) void active_um(const float* __restrict__ ep,
                                                 const float* __restrict__ sel,
                                                 float* __restrict__ um,
                                                 const int* __restrict__ flag){
  if (flag[0]) return;
  int b = blockIdx.x, t = threadIdx.x;
  float s = (t<SS) ? ep[b*SS+t]*sel[b*SS+t] : 0.f;
  s = bsum(s);
  if (t==0) um[b] *= (s >= 0.1f) ? 1.f : 0.f;
}
__global__ __launch_bounds__(64) void done_kernel(const float* __restrict__ um, int* __restrict__ flag){
  float v = um[threadIdx.x];
  unsigned long long b = __ballot(v > 0.f);
  if (threadIdx.x==0) flag[0] = (b==0ULL) ? 1 : 0;
}

// ---------------- outputs ----------------
__global__ __launch_bounds__(256) void output_kernel(const float* __restrict__ sq,
                                                     const float* __restrict__ mk,
                                                     float* __restrict__ out){
  int r = blockIdx.x; int b = r/SS, i = r%SS;
  if (i<1 || i>128) return;
  float m = mk[r]; int t=threadIdx.x;
  #pragma unroll
  for (int q=0;q<4;q++){
    int j = t+q*256;
    out[((size_t)b*128 + (i-1))*DD + j] = sq[(size_t)r*DD + j]*m;
  }
}
__global__ __launch_bounds__(256) void gstate_kernel(const float* __restrict__ sq,
                                                     const float* __restrict__ mk,
                                                     const float* __restrict__ lastm,
                                                     float* __restrict__ outg){
  int b = blockIdx.x; int t=threadIdx.x;
  #pragma unroll
  for (int q=0;q<4;q++){
    int j = t+q*256;
    float acc=0.f;
    for (int i=0;i<SS;i++){
      float w = lastm[b*SS+i]*mk[b*SS+i];
      acc = fmaf(w, sq[((size_t)(b*SS+i))*DD + j], acc);
    }
    outg[(size_t)b*DD + j] = acc;
  }
}

extern "C" void kernel_launch(void* const* d_in, const int* in_sizes, int n_in,
                              void* d_out, int out_size, void* d_ws, size_t ws_size,
                              hipStream_t stream) {
  const float* sequence   = (const float*)d_in[0];
  const float* input_mask = (const float*)d_in[1];
  const float* START      = (const float*)d_in[2];
  const float* END        = (const float*)d_in[3];
  const float* W_conv     = (const float*)d_in[4];
  const float* b_conv     = (const float*)d_in[5];
  const float* W_scorer   = (const float*)d_in[6];
  const float* b_scorer   = (const float*)d_in[7];
  const float* W_init     = (const float*)d_in[8];
  const float* b_init     = (const float*)d_in[9];
  const float* W_cell1    = (const float*)d_in[10];
  const float* b_cell1    = (const float*)d_in[11];
  const float* W_cell2    = (const float*)d_in[12];
  const float* b_cell2    = (const float*)d_in[13];
  const float* ln1g       = (const float*)d_in[14];
  const float* ln1b       = (const float*)d_in[15];
  const float* ln2g       = (const float*)d_in[16];
  const float* ln2b       = (const float*)d_in[17];

  float* ws = (float*)d_ws;
  const size_t U = (size_t)MM*DD;
  float* sq   = ws;
  float* l1   = ws + U;
  float* r1   = ws + 2*U;
  float* l2   = ws + 3*U;   // also hid-chunk
  float* r2   = ws + 4*U;   // also cont-chunk
  float* Lm   = ws + 5*U;
  float* Rm   = Lm + (size_t)NB*SS*LSTR;
  float* maskv= Rm + (size_t)NB*SS*LSTR;
  float* sel  = maskv + MM;
  float* lastm= sel + MM;
  float* endm = lastm + MM;
  float* ep   = endm + MM;
  float* scb  = ep + MM;
  float* tpb  = scb + MM;
  float* spart= tpb + MM;          // MM*16
  float* umb  = spart + (size_t)MM*16;
  float* part = umb + NB;
  float* gmx  = part + 64;
  int*   flag = (int*)(gmx + 4);
  // optional persistent f16 W^T planes (PRE tier)
  size_t used_floats = (size_t)((float*)(flag+4) - ws);
  used_floats = (used_floats + 7) & ~(size_t)7;
  _Float16* WTc_h = (_Float16*)(ws + used_floats);
  const size_t SC = (size_t)1024*5120, S1 = (size_t)4096*2048, S2 = (size_t)4096*4096;
  _Float16* WTc_l = WTc_h + SC;
  _Float16* WT1_h = WTc_l + SC;
  _Float16* WT1_l = WT1_h + S1;
  _Float16* WT2_h = WT1_l + S1;
  _Float16* WT2_l = WT2_h + S2;
  size_t need_pre = (size_t)((char*)(WT2_l + S2) - (char*)d_ws);
  const bool pre = ws_size >= need_pre;

  build_masks<<<NB,256,0,stream>>>(input_mask, maskv, sel, lastm, endm, ep, umb, flag);
  build_seq<<<MM,256,0,stream>>>(sequence, START, END, maskv, endm, r1);
  GemmSrc si; si.a[0]=r1; si.a[1]=r1; si.a[2]=r1; si.a[3]=r1; si.a[4]=r1;
  gemm_f32<<<dim3(8,65),256,0,stream>>>(si, DD, W_init, b_init, l2, DD, DD, DD, 0, flag);
  ln1_kernel<<<MM,256,0,stream>>>(l2, ln1g, ln1b, maskv, sq);

  if (pre){
    wtranspose<<<dim3(160,32),256,0,stream>>>(W_conv,  WTc_h, WTc_l, 5120, 1024);
    wtranspose<<<dim3(64,128),256,0,stream>>>(W_cell1, WT1_h, WT1_l, 2048, 4096);
    wtranspose<<<dim3(128,128),256,0,stream>>>(W_cell2, WT2_h, WT2_l, 4096, 4096);
  }

  for (int it=0; it<25; ++it){
    neighbor_kernel<<<(MM+255)/256,256,0,stream>>>(ep, maskv, Lm, Rm, flag);
    bgemm<<<dim3(8,3,NB),256,0,stream>>>(Lm, sq, l1, flag);
    bgemm<<<dim3(8,3,NB),256,0,stream>>>(Rm, sq, r1, flag);
    bgemm<<<dim3(8,3,NB),256,0,stream>>>(Lm, l1, l2, flag);
    bgemm<<<dim3(8,3,NB),256,0,stream>>>(Rm, r1, r2, flag);
    GemmSrc s5; s5.a[0]=l2; s5.a[1]=l1; s5.a[2]=sq; s5.a[3]=r1; s5.a[4]=r2;
    if (pre)
      gemm_mfma<true ><<<dim3(8,65),256,0,stream>>>(s5, DD, WTc_h, WTc_l, nullptr, 0, b_conv, nullptr, 0, 5120, 2, flag, spart, W_scorer);
    else
      gemm_mfma<false><<<dim3(8,65),256,0,stream>>>(s5, DD, nullptr, nullptr, W_conv, 1024, b_conv, nullptr, 0, 5120, 2, flag, spart, W_scorer);
    scorer_final<<<(MM+255)/256,256,0,stream>>>(spart, b_scorer, scb, flag);
    max1<<<64,256,0,stream>>>(scb, part, flag);
    max2<<<1,64,0,stream>>>(part, gmx, flag);
    tp_kernel<<<(MM+255)/256,256,0,stream>>>(scb, sel, umb, gmx, tpb, flag);
    for (int c=0;c<5;c++){
      long row0 = (long)c*CROWS;
      GemmSrc s2; s2.a[0]=l1+row0*DD; s2.a[1]=sq+row0*DD; s2.a[2]=s2.a[1]; s2.a[3]=s2.a[1]; s2.a[4]=s2.a[1];
      GemmSrc s3; s3.a[0]=l2; s3.a[1]=l2+DD; s3.a[2]=l2+2*DD; s3.a[3]=l2+3*DD; s3.a[4]=l2;
      if (pre){
        gemm_mfma<true ><<<dim3(32,13),256,0,stream>>>(s2, DD,   WT1_h, WT1_l, nullptr, 0, b_cell1, l2, 4096, 2048, 1, flag, nullptr, nullptr);
        gemm_mfma<true ><<<dim3(32,13),256,0,stream>>>(s3, 4096, WT2_h, WT2_l, nullptr, 0, b_cell2, r2, 4096, 4096, 0, flag, nullptr, nullptr);
      } else {
        gemm_mfma<false><<<dim3(32,13),256,0,stream>>>(s2, DD,   nullptr, nullptr, W_cell1, 4096, b_cell1, l2, 4096, 2048, 1, flag, nullptr, nullptr);
        gemm_mfma<false><<<dim3(32,13),256,0,stream>>>(s3, 4096, nullptr, nullptr, W_cell2, 4096, b_cell2, r2, 4096, 4096, 0, flag, nullptr, nullptr);
      }
      update_kernel<<<CROWS,256,0,stream>>>(r2, l1, sq, tpb, ln2g, ln2b, flag, row0);
    }
    ep_update<<<(MM+255)/256,256,0,stream>>>(ep, Rm, tpb, flag);
    active_um<<<NB,256,0,stream>>>(ep, sel, umb, flag);
    done_kernel<<<1,64,0,stream>>>(umb, flag);
  }

  float* out = (float*)d_out;
  output_kernel<<<MM,256,0,stream>>>(sq, maskv, out);
  gstate_kernel<<<NB,256,0,stream>>>(sq, maskv, lastm, out + (size_t)NB*128*DD);
}